// Round 1
// baseline (303.036 us; speedup 1.0000x reference)
//
#include <hip/hip_runtime.h>
#include <math.h>

#define B 16
#define C 2
#define T 2000
#define F 257
#define NC 50            // chunks per (b,f)
#define L  (T / NC)      // 40 timesteps per chunk

#define RES_SIZE   (B * C * T * F * 2)   // 32,896,000
#define OFF_SFINAL (RES_SIZE)            // + B*F
#define OFF_SMOOTH (RES_SIZE + B * F)    // + B*T*F

__device__ __forceinline__ float sigmoidf_(float x) {
    return 1.0f / (1.0f + expf(-x));
}

// Phase 1: per-chunk carries (recurrence with s=0 over L steps)
__global__ void k_carries(const float* __restrict__ input,
                          const float* __restrict__ alpha_param,
                          float* __restrict__ carry) {
    int tid = blockIdx.x * blockDim.x + threadIdx.x;
    const int N = B * F * NC;
    if (tid >= N) return;
    int f = tid % F;
    int r = tid / F;
    int c = r % NC;
    int b = r / NC;

    float a = sigmoidf_(alpha_param[f]);
    float beta = 1.0f - a;

    const float2* inp = (const float2*)input + ((size_t)(b * C + 0) * T + (size_t)c * L) * F + f;
    float s = 0.0f;
#pragma unroll 8
    for (int t = 0; t < L; ++t) {
        float2 v = inp[(size_t)t * F];
        float x = v.x * v.x + v.y * v.y;
        s = beta * s + a * x;
    }
    carry[(b * NC + c) * F + f] = s;
}

// Phase 2: scan over chunks; emit chunk-start states, s_final
__global__ void k_scan(const float* __restrict__ s_1,
                       const float* __restrict__ alpha_param,
                       const float* __restrict__ carry,
                       float* __restrict__ chunkstart,
                       float* __restrict__ out) {
    int tid = blockIdx.x * blockDim.x + threadIdx.x;
    const int N = B * F;
    if (tid >= N) return;
    int f = tid % F;
    int b = tid / F;

    float a = sigmoidf_(alpha_param[f]);
    float beta = 1.0f - a;
    float bL = 1.0f;
#pragma unroll
    for (int i = 0; i < L; ++i) bL *= beta;

    float s = s_1[b * F + f];
    for (int c = 0; c < NC; ++c) {
        int idx = (b * NC + c) * F + f;
        chunkstart[idx] = s;
        s = bL * s + carry[idx];
    }
    out[OFF_SFINAL + b * F + f] = s;  // s_final (pre-sqrt), [B,1,F,1]
}

// Phase 3a: channel 0 — exact per-step recurrence from chunk-start; smooth + res
__global__ void k_final0(const float* __restrict__ input,
                         const float* __restrict__ alpha_param,
                         const float* __restrict__ weights,
                         const float* __restrict__ bias,
                         const float* __restrict__ chunkstart,
                         float* __restrict__ out) {
    int tid = blockIdx.x * blockDim.x + threadIdx.x;
    const int N = B * F * NC;
    if (tid >= N) return;
    int f = tid % F;
    int r = tid / F;
    int c = r % NC;
    int b = r / NC;

    float a = sigmoidf_(alpha_param[f]);
    float beta = 1.0f - a;
    float w0 = weights[0 * F + f];
    float b0 = bias[0 * F + f];

    const float2* inp = (const float2*)input + ((size_t)(b * C + 0) * T + (size_t)c * L) * F + f;
    float2* res = (float2*)out + ((size_t)(b * C + 0) * T + (size_t)c * L) * F + f;
    float* smooth = out + OFF_SMOOTH + ((size_t)b * T + (size_t)c * L) * F + f;

    float s = chunkstart[(b * NC + c) * F + f];
#pragma unroll 8
    for (int t = 0; t < L; ++t) {
        float2 v = inp[(size_t)t * F];
        float x = v.x * v.x + v.y * v.y;
        s = beta * s + a * x;
        float sm = sqrtf(s);
        float inv = 1.0f / (sm + 1e-8f);
        float2 rr;
        rr.x = v.x * inv * w0 + b0;
        rr.y = v.y * inv * w0 + b0;
        res[(size_t)t * F] = rr;
        smooth[(size_t)t * F] = sm;
    }
}

// Phase 3b: channel 1 — pure elementwise
__global__ void k_final1(const float* __restrict__ input,
                         const float* __restrict__ weights,
                         const float* __restrict__ bias,
                         float* __restrict__ out) {
    int tid = blockIdx.x * blockDim.x + threadIdx.x;
    const int N = B * T * F;
    if (tid >= N) return;
    int f = tid % F;
    int r = tid / F;
    int t = r % T;
    int b = r / T;

    float w1 = weights[1 * F + f];
    float b1 = bias[1 * F + f];

    const float2* inp = (const float2*)input + ((size_t)(b * C + 1) * T + t) * F + f;
    float2* res = (float2*)out + ((size_t)(b * C + 1) * T + t) * F + f;

    float2 v = *inp;
    float x = v.x * v.x + v.y * v.y;
    float sm = sqrtf(x);
    float inv = 1.0f / (sm + 1e-8f);
    float2 rr;
    rr.x = v.x * inv * w1 + b1;
    rr.y = v.y * inv * w1 + b1;
    *res = rr;
}

extern "C" void kernel_launch(void* const* d_in, const int* in_sizes, int n_in,
                              void* d_out, int out_size, void* d_ws, size_t ws_size,
                              hipStream_t stream) {
    const float* input       = (const float*)d_in[0];
    const float* s_1         = (const float*)d_in[1];
    const float* weights     = (const float*)d_in[2];
    const float* bias        = (const float*)d_in[3];
    const float* alpha_param = (const float*)d_in[4];
    float* out = (float*)d_out;

    float* carry      = (float*)d_ws;                 // B*NC*F floats
    float* chunkstart = (float*)d_ws + B * NC * F;    // B*NC*F floats

    const int N1 = B * F * NC;   // 205,600
    const int N2 = B * F;        // 4,112
    const int N3 = B * T * F;    // 8,224,000

    k_carries<<<(N1 + 255) / 256, 256, 0, stream>>>(input, alpha_param, carry);
    k_scan<<<(N2 + 255) / 256, 256, 0, stream>>>(s_1, alpha_param, carry, chunkstart, out);
    k_final0<<<(N1 + 255) / 256, 256, 0, stream>>>(input, alpha_param, weights, bias, chunkstart, out);
    k_final1<<<(N3 + 255) / 256, 256, 0, stream>>>(input, weights, bias, out);
}